// Round 4
// baseline (3027.214 us; speedup 1.0000x reference)
//
#include <hip/hip_runtime.h>
#include <hip/hip_bf16.h>

// MAHGN: 2-layer hetero GAT, fp32.
// Round 4: CSR build rewritten as two-level LDS-privatized multisplit
// (no global atomics). Edge gather unchanged (online softmax over CSR).

static constexpr int kNUser = 200000;
static constexpr int kNArt  = 100000;
static constexpr int kNCat  = 500;
static constexpr size_t SZ_U = (size_t)kNUser * 64;
static constexpr size_t SZ_A = (size_t)kNArt * 64;
static constexpr size_t SZ_C = (size_t)kNCat * 64;
static constexpr size_t SZ_X = SZ_U + SZ_A + SZ_C;
static constexpr int CHUNK = 4096;

// ---------------- dense transforms ----------------

// hs = x @ W (64x64) + fused a_s. 256 thr: 64x64 tile, thread = 4x4 register tile.
__global__ __launch_bounds__(256, 4) void k_transform(const float* __restrict__ x,
    const float* __restrict__ W, const float* __restrict__ att,
    float* __restrict__ hs, float* __restrict__ a_s, int Ns)
{
  __shared__ float sXt[64 * 68];
  __shared__ float sW[64 * 64];
  __shared__ float sAtt[64];
  int tid = threadIdx.x;
  int r0 = blockIdx.x * 64;

  {
    const float4* w4 = (const float4*)W;
    float4* s4 = (float4*)sW;
    #pragma unroll
    for (int i = 0; i < 4; ++i) s4[tid + 256 * i] = w4[tid + 256 * i];
  }
  if (tid < 64) sAtt[tid] = att[tid];
  {
    int r = tid >> 4, kq = tid & 15;
    #pragma unroll
    for (int rg = 0; rg < 4; ++rg) {
      int row = r0 + rg * 16 + r;
      float4 xv = make_float4(0.f, 0.f, 0.f, 0.f);
      if (row < Ns) xv = *(const float4*)(x + (size_t)row * 64 + kq * 4);
      sXt[(kq * 4 + 0) * 68 + rg * 16 + r] = xv.x;
      sXt[(kq * 4 + 1) * 68 + rg * 16 + r] = xv.y;
      sXt[(kq * 4 + 2) * 68 + rg * 16 + r] = xv.z;
      sXt[(kq * 4 + 3) * 68 + rg * 16 + r] = xv.w;
    }
  }
  __syncthreads();

  int c4 = tid & 15, r4 = tid >> 4;
  float acc[4][4];
  #pragma unroll
  for (int i = 0; i < 4; ++i)
    #pragma unroll
    for (int j = 0; j < 4; ++j) acc[i][j] = 0.f;

  #pragma unroll 16
  for (int k = 0; k < 64; ++k) {
    float4 xv = *(const float4*)&sXt[k * 68 + r4 * 4];
    float4 wv = *(const float4*)&sW[k * 64 + c4 * 4];
    const float* xf = &xv.x;
    const float* wf = &wv.x;
    #pragma unroll
    for (int i = 0; i < 4; ++i)
      #pragma unroll
      for (int j = 0; j < 4; ++j) acc[i][j] += xf[i] * wf[j];
  }

  float attv[4];
  #pragma unroll
  for (int j = 0; j < 4; ++j) attv[j] = sAtt[c4 * 4 + j];
  int h = c4 >> 2;
  #pragma unroll
  for (int i = 0; i < 4; ++i) {
    int row = r0 + r4 * 4 + i;
    bool ok = row < Ns;
    if (ok) *(float4*)(hs + (size_t)row * 64 + c4 * 4) =
        make_float4(acc[i][0], acc[i][1], acc[i][2], acc[i][3]);
    float p = acc[i][0] * attv[0] + acc[i][1] * attv[1] +
              acc[i][2] * attv[2] + acc[i][3] * attv[3];
    p += __shfl_xor(p, 1, 64);
    p += __shfl_xor(p, 2, 64);
    if ((c4 & 3) == 0 && ok) a_s[(size_t)row * 4 + h] = p;
  }
}

// a_d = x_d @ vd (64x4 GEMV); vd folded from Wd,att per block.
__global__ __launch_bounds__(256) void k_ad(const float* __restrict__ x,
    const float* __restrict__ Wd, const float* __restrict__ att,
    float* __restrict__ a_d, int Nd)
{
  __shared__ float sV[256];
  int tid = threadIdx.x;
  {
    int k = tid >> 2, h = tid & 3;
    float s = 0.f;
    #pragma unroll
    for (int c = 0; c < 16; ++c) s += Wd[k * 64 + h * 16 + c] * att[h * 16 + c];
    sV[k * 4 + h] = s;
  }
  __syncthreads();
  int n = blockIdx.x * 256 + tid;
  if (n >= Nd) return;
  const float4* x4 = (const float4*)(x + (size_t)n * 64);
  float a0 = 0.f, a1 = 0.f, a2 = 0.f, a3 = 0.f;
  #pragma unroll
  for (int k4 = 0; k4 < 16; ++k4) {
    float4 xv = x4[k4];
    const float* f = &xv.x;
    #pragma unroll
    for (int j = 0; j < 4; ++j) {
      int k = k4 * 4 + j;
      float xk = f[j];
      a0 += xk * sV[k * 4 + 0];
      a1 += xk * sV[k * 4 + 1];
      a2 += xk * sV[k * 4 + 2];
      a3 += xk * sV[k * 4 + 3];
    }
  }
  *(float4*)(a_d + (size_t)n * 4) = make_float4(a0, a1, a2, a3);
}

// ---------------- CSR build: two-level LDS multisplit ----------------

// A1: per-chunk coarse histogram (bins of 1<<shift dst), LDS atomics only.
__global__ __launch_bounds__(256) void k_bhist(const int* __restrict__ col, int E,
    int nblk, int nbin, int shift, int* __restrict__ bh)
{
  __shared__ int h[1024];
  int tid = threadIdx.x;
  for (int j = tid; j < nbin; j += 256) h[j] = 0;
  __syncthreads();
  int b = blockIdx.x;
  int lo = b * CHUNK, hi = min(E, lo + CHUNK);
  for (int i = lo + tid; i < hi; i += 256) atomicAdd(&h[col[i] >> shift], 1);
  __syncthreads();
  for (int j = tid; j < nbin; j += 256) bh[j * nblk + b] = h[j];   // bin-major
}

// A2: one block. In-place exclusive scan over blocks per bin, then bin bases.
__global__ __launch_bounds__(1024) void k_bscan(int* __restrict__ bh, int nblk,
    int nbin, int* __restrict__ binbase)
{
  __shared__ int tot[1024];
  int tid = threadIdx.x;
  int s = 0;
  if (tid < nbin) {
    int base = tid * nblk;
    for (int b = 0; b < nblk; ++b) { int v = bh[base + b]; bh[base + b] = s; s += v; }
  }
  tot[tid] = (tid < nbin) ? s : 0;
  __syncthreads();
  for (int off = 1; off < 1024; off <<= 1) {
    int t = (tid >= off) ? tot[tid - off] : 0;
    __syncthreads();
    tot[tid] += t;
    __syncthreads();
  }
  if (tid < nbin) binbase[tid] = tot[tid] - s;   // exclusive
  if (tid == 1023) binbase[nbin] = tot[1023];    // grand total = E
}

// A3: scatter into coarse buckets; rank via LDS cursors (disjoint ranges/block).
__global__ __launch_bounds__(256) void k_bscat(const int* __restrict__ row,
    const int* __restrict__ col, int E, int nblk, int nbin, int shift,
    const int* __restrict__ bh, const int* __restrict__ binbase,
    int* __restrict__ trow, int* __restrict__ tcol)
{
  __shared__ int cur[1024];
  int tid = threadIdx.x;
  int b = blockIdx.x;
  for (int j = tid; j < nbin; j += 256) cur[j] = binbase[j] + bh[j * nblk + b];
  __syncthreads();
  int lo = b * CHUNK, hi = min(E, lo + CHUNK);
  for (int i = lo + tid; i < hi; i += 256) {
    int c = col[i];
    int p = atomicAdd(&cur[c >> shift], 1);
    trow[p] = row[i];
    if (tcol) tcol[p] = c;
  }
}

// B: one block per coarse bin: fine hist (256 dst) + LDS scan -> rowptr + rows.
__global__ __launch_bounds__(256) void k_fine(const int* __restrict__ trow,
    const int* __restrict__ tcol, const int* __restrict__ binbase,
    int* __restrict__ rowptr, int* __restrict__ rows, int Nd, int nbin)
{
  __shared__ int h[256], sc[256], cur[256];
  int tid = threadIdx.x;
  int bin = blockIdx.x;
  int s = binbase[bin], e = binbase[bin + 1];
  h[tid] = 0;
  __syncthreads();
  for (int k = s + tid; k < e; k += 256) atomicAdd(&h[tcol[k] & 255], 1);
  __syncthreads();
  int own = h[tid];
  sc[tid] = own;
  __syncthreads();
  for (int off = 1; off < 256; off <<= 1) {
    int t = (tid >= off) ? sc[tid - off] : 0;
    __syncthreads();
    sc[tid] += t;
    __syncthreads();
  }
  int excl = sc[tid] - own;
  int dst = bin * 256 + tid;
  if (dst < Nd) rowptr[dst] = s + excl;
  cur[tid] = s + excl;
  if (bin == 0 && tid == 0) rowptr[Nd] = binbase[nbin];
  __syncthreads();
  for (int k = s + tid; k < e; k += 256) {
    int p = atomicAdd(&cur[tcol[k] & 255], 1);
    rows[p] = trow[k];
  }
}

// small-Nd path: rowptr is just binbase (bins of 1).
__global__ void k_rp(const int* __restrict__ binbase, int* __restrict__ rowptr, int Nd) {
  int i = blockIdx.x * 256 + threadIdx.x;
  if (i <= Nd) rowptr[i] = binbase[i];
}

// ---------------- gather (online softmax) ----------------

__global__ __launch_bounds__(256) void k_gather16(const int* __restrict__ rowptr,
    const int* __restrict__ rows, const float* __restrict__ a_s,
    const float* __restrict__ a_d, const float* __restrict__ hs,
    float* __restrict__ out, int Nd)
{
  int tid = threadIdx.x;
  int g = tid >> 4, lane = tid & 15, h = lane >> 2;
  int n = blockIdx.x * 16 + g;
  if (n >= Nd) return;
  float adh = a_d[(size_t)n * 4 + h];
  int start = rowptr[n], end = rowptr[n + 1];
  float m = -INFINITY, den = 0.f;
  float ax = 0.f, ay = 0.f, az = 0.f, aw = 0.f;
  for (int k = start; k < end; ++k) {
    int row = rows[k];
    float v = a_s[(size_t)row * 4 + h] + adh;
    v = v >= 0.f ? v : 0.2f * v;
    float mn = fmaxf(m, v);
    float c = __expf(m - mn);
    float p = __expf(v - mn);
    float4 hv = *(const float4*)(hs + (size_t)row * 64 + lane * 4);
    den = den * c + p;
    ax = ax * c + p * hv.x;
    ay = ay * c + p * hv.y;
    az = az * c + p * hv.z;
    aw = aw * c + p * hv.w;
    m = mn;
  }
  float inv = 1.f / (den + 1e-16f);
  float4* op = (float4*)(out + (size_t)n * 64) + lane;
  float4 prev = *op;
  prev.x += ax * inv; prev.y += ay * inv; prev.z += az * inv; prev.w += aw * inv;
  *op = prev;
}

__global__ __launch_bounds__(256) void k_gatherB(const int* __restrict__ rowptr,
    const int* __restrict__ rows, const float* __restrict__ a_s,
    const float* __restrict__ a_d, const float* __restrict__ hs,
    float* __restrict__ out)
{
  __shared__ float sm[64], sden[64], sacc[1024];
  int n = blockIdx.x;
  int tid = threadIdx.x;
  int sg = tid >> 4, lane = tid & 15, h = lane >> 2;
  float adh = a_d[(size_t)n * 4 + h];
  int start = rowptr[n], end = rowptr[n + 1];
  float m = -INFINITY, den = 0.f;
  float ax = 0.f, ay = 0.f, az = 0.f, aw = 0.f;
  for (int k = start + sg; k < end; k += 16) {
    int row = rows[k];
    float v = a_s[(size_t)row * 4 + h] + adh;
    v = v >= 0.f ? v : 0.2f * v;
    float mn = fmaxf(m, v);
    float c = __expf(m - mn);
    float p = __expf(v - mn);
    float4 hv = *(const float4*)(hs + (size_t)row * 64 + lane * 4);
    den = den * c + p;
    ax = ax * c + p * hv.x;
    ay = ay * c + p * hv.y;
    az = az * c + p * hv.z;
    aw = aw * c + p * hv.w;
    m = mn;
  }
  sacc[sg * 64 + lane * 4 + 0] = ax;
  sacc[sg * 64 + lane * 4 + 1] = ay;
  sacc[sg * 64 + lane * 4 + 2] = az;
  sacc[sg * 64 + lane * 4 + 3] = aw;
  if ((lane & 3) == 0) { sm[sg * 4 + h] = m; sden[sg * 4 + h] = den; }
  __syncthreads();
  if (tid < 64) {
    int hh = tid >> 4;
    float M = -INFINITY;
    #pragma unroll
    for (int g2 = 0; g2 < 16; ++g2) M = fmaxf(M, sm[g2 * 4 + hh]);
    if (M == -INFINITY) M = 0.f;
    float D = 0.f, A = 0.f;
    #pragma unroll
    for (int g2 = 0; g2 < 16; ++g2) {
      float mv = sm[g2 * 4 + hh];
      float c = (mv == -INFINITY) ? 0.f : __expf(mv - M);
      D += sden[g2 * 4 + hh] * c;
      A += sacc[g2 * 64 + tid] * c;
    }
    out[(size_t)n * 64 + tid] += A / (D + 1e-16f);
  }
}

// ---------------- epilogue ----------------

__global__ void k_act(float* __restrict__ x, const float* __restrict__ b0,
                      const float* __restrict__ b1, const float* __restrict__ b2,
                      const float* __restrict__ b3, int nb, int n)
{
  int i = blockIdx.x * blockDim.x + threadIdx.x;
  if (i >= n) return;
  int d = i & 63;
  float bs = b0[d] + b1[d];
  if (nb == 4) bs += b2[d] + b3[d];
  float v = x[i] + bs;
  x[i] = v >= 0.f ? v : 0.01f * v;
}

__global__ void k_final(const float* __restrict__ x0, const float* __restrict__ x1,
                        const float* __restrict__ x2, float* __restrict__ out, int n)
{
  int i = blockIdx.x * blockDim.x + threadIdx.x;
  if (i < n) out[i] = (x0[i] + x1[i] + x2[i]) * (1.f / 3.f);
}

// ---------------- launch ----------------

extern "C" void kernel_launch(void* const* d_in, const int* in_sizes, int n_in,
                              void* d_out, int out_size, void* d_ws, size_t ws_size,
                              hipStream_t stream)
{
  static const int ECNT[8] = {1000000, 1000000, 500000, 500000, 100000, 100000, 500000, 500000};
  static const int ESRC[8] = {0, 1, 0, 0, 1, 2, 0, 2};   // 0=user 1=article 2=category
  static const int EDST[8] = {1, 0, 0, 0, 2, 1, 2, 0};
  const int NSZ[3] = {kNUser, kNArt, kNCat};

  const float* x0[3] = {(const float*)d_in[0], (const float*)d_in[1], (const float*)d_in[2]};
  const float* Wsrc = (const float*)d_in[3];
  const float* Wdst = (const float*)d_in[4];
  const float* attS = (const float*)d_in[5];
  const float* attD = (const float*)d_in[6];
  const float* bias = (const float*)d_in[7];
  const int* ei[8];
  for (int t = 0; t < 8; ++t) ei[t] = (const int*)d_in[8 + t];

  float* ws = (float*)d_ws;
  size_t off = 0;
  auto alloc = [&](size_t nelem) { float* p = ws + off; off += nelem; return p; };
  float* xb0 = alloc(SZ_X);
  float* xb1 = alloc(SZ_X);
  float* hs  = alloc((size_t)kNUser * 64);
  float* a_s = alloc((size_t)kNUser * 4);
  float* a_d = alloc((size_t)kNUser * 4);
  int* rowptrA = (int*)alloc(1001008);
  int* rowsA   = (int*)alloc(4200000);
  int* tmp_row = (int*)alloc(1000000);
  int* tmp_col = (int*)alloc(1000000);
  int* blockhist = (int*)alloc(200704);      // max nbin(782) * nblk(245)
  int* binbase   = (int*)alloc(1032);

  int* rowptr_t[8]; int* rows_t[8];
  {
    size_t ro = 0, eo = 0;
    for (int t = 0; t < 8; ++t) {
      int Nd = NSZ[EDST[t]];
      rowptr_t[t] = rowptrA + ro; ro += (size_t)Nd + 1;
      rows_t[t]   = rowsA + eo;   eo += (size_t)ECNT[t];
    }
  }

  // ---- CSR build: two-level LDS multisplit (no global atomics) ----
  for (int t = 0; t < 8; ++t) {
    int Nd = NSZ[EDST[t]], E = ECNT[t];
    const int* row = ei[t];
    const int* col = ei[t] + E;
    int shift = (Nd <= 1024) ? 0 : 8;
    int nbin = ((Nd - 1) >> shift) + 1;
    int nblk = (E + CHUNK - 1) / CHUNK;
    k_bhist<<<nblk, 256, 0, stream>>>(col, E, nblk, nbin, shift, blockhist);
    k_bscan<<<1, 1024, 0, stream>>>(blockhist, nblk, nbin, binbase);
    if (shift == 0) {
      // bins of 1 dst: coarse scatter is the final sort
      k_bscat<<<nblk, 256, 0, stream>>>(row, col, E, nblk, nbin, 0,
                                        blockhist, binbase, rows_t[t], nullptr);
      k_rp<<<(Nd + 256) / 256, 256, 0, stream>>>(binbase, rowptr_t[t], Nd);
    } else {
      k_bscat<<<nblk, 256, 0, stream>>>(row, col, E, nblk, nbin, 8,
                                        blockhist, binbase, tmp_row, tmp_col);
      k_fine<<<nbin, 256, 0, stream>>>(tmp_row, tmp_col, binbase,
                                       rowptr_t[t], rows_t[t], Nd, nbin);
    }
  }

  float* xb[2][3] = {{xb0, xb0 + SZ_U, xb0 + SZ_U + SZ_A},
                     {xb1, xb1 + SZ_U, xb1 + SZ_U + SZ_A}};
  const float* xcur[3] = {x0[0], x0[1], x0[2]};
  for (int l = 0; l < 2; ++l) {
    hipMemsetAsync(xb[l][0], 0, SZ_X * sizeof(float), stream);
    for (int t = 0; t < 8; ++t) {
      int s = ESRC[t], d = EDST[t];
      int Ns = NSZ[s], Nd = NSZ[d];
      const float* Ws = Wsrc + (size_t)(l * 8 + t) * 4096;
      const float* Wd = Wdst + (size_t)(l * 8 + t) * 4096;
      const float* aS = attS + (size_t)(l * 8 + t) * 64;
      const float* aD = attD + (size_t)(l * 8 + t) * 64;
      k_transform<<<(Ns + 63) / 64, 256, 0, stream>>>(xcur[s], Ws, aS, hs, a_s, Ns);
      k_ad<<<(Nd + 255) / 256, 256, 0, stream>>>(xcur[d], Wd, aD, a_d, Nd);
      if (Nd <= 512)
        k_gatherB<<<Nd, 256, 0, stream>>>(rowptr_t[t], rows_t[t], a_s, a_d, hs, xb[l][d]);
      else
        k_gather16<<<(Nd + 15) / 16, 256, 0, stream>>>(rowptr_t[t], rows_t[t], a_s, a_d, hs, xb[l][d], Nd);
    }
    const float* bl = bias + (size_t)l * 8 * 64;
    // dst lists: user {1,2,3,7}, article {0,5}, category {4,6}
    k_act<<<((int)SZ_U + 255) / 256, 256, 0, stream>>>(xb[l][0], bl + 64, bl + 128, bl + 192, bl + 448, 4, (int)SZ_U);
    k_act<<<((int)SZ_A + 255) / 256, 256, 0, stream>>>(xb[l][1], bl + 0,  bl + 320, bl, bl, 2, (int)SZ_A);
    k_act<<<((int)SZ_C + 255) / 256, 256, 0, stream>>>(xb[l][2], bl + 256, bl + 384, bl, bl, 2, (int)SZ_C);
    xcur[0] = xb[l][0]; xcur[1] = xb[l][1]; xcur[2] = xb[l][2];
  }
  k_final<<<((int)SZ_U + 255) / 256, 256, 0, stream>>>(x0[0], xb[0][0], xb[1][0], (float*)d_out, (int)SZ_U);
  k_final<<<((int)SZ_A + 255) / 256, 256, 0, stream>>>(x0[1], xb[0][1], xb[1][1], (float*)d_out + SZ_U, (int)SZ_A);
}

// Round 5
// 1938.361 us; speedup vs baseline: 1.5617x; 1.5617x over previous
//
#include <hip/hip_runtime.h>
#include <hip/hip_bf16.h>

// MAHGN: 2-layer hetero GAT, fp32.
// Round 5: multisplit CSR kept, but the serial one-block scan (R4's k_bscan,
// ~360us each) replaced by a parallel 3-kernel flat scan over bh (coalesced).

static constexpr int kNUser = 200000;
static constexpr int kNArt  = 100000;
static constexpr int kNCat  = 500;
static constexpr size_t SZ_U = (size_t)kNUser * 64;
static constexpr size_t SZ_A = (size_t)kNArt * 64;
static constexpr size_t SZ_C = (size_t)kNCat * 64;
static constexpr size_t SZ_X = SZ_U + SZ_A + SZ_C;
static constexpr int CHUNK = 4096;

// ---------------- dense transforms ----------------

// hs = x @ W (64x64) + fused a_s. 256 thr: 64x64 tile, thread = 4x4 register tile.
__global__ __launch_bounds__(256, 4) void k_transform(const float* __restrict__ x,
    const float* __restrict__ W, const float* __restrict__ att,
    float* __restrict__ hs, float* __restrict__ a_s, int Ns)
{
  __shared__ float sXt[64 * 68];
  __shared__ float sW[64 * 64];
  __shared__ float sAtt[64];
  int tid = threadIdx.x;
  int r0 = blockIdx.x * 64;

  {
    const float4* w4 = (const float4*)W;
    float4* s4 = (float4*)sW;
    #pragma unroll
    for (int i = 0; i < 4; ++i) s4[tid + 256 * i] = w4[tid + 256 * i];
  }
  if (tid < 64) sAtt[tid] = att[tid];
  {
    int r = tid >> 4, kq = tid & 15;
    #pragma unroll
    for (int rg = 0; rg < 4; ++rg) {
      int row = r0 + rg * 16 + r;
      float4 xv = make_float4(0.f, 0.f, 0.f, 0.f);
      if (row < Ns) xv = *(const float4*)(x + (size_t)row * 64 + kq * 4);
      sXt[(kq * 4 + 0) * 68 + rg * 16 + r] = xv.x;
      sXt[(kq * 4 + 1) * 68 + rg * 16 + r] = xv.y;
      sXt[(kq * 4 + 2) * 68 + rg * 16 + r] = xv.z;
      sXt[(kq * 4 + 3) * 68 + rg * 16 + r] = xv.w;
    }
  }
  __syncthreads();

  int c4 = tid & 15, r4 = tid >> 4;
  float acc[4][4];
  #pragma unroll
  for (int i = 0; i < 4; ++i)
    #pragma unroll
    for (int j = 0; j < 4; ++j) acc[i][j] = 0.f;

  #pragma unroll 16
  for (int k = 0; k < 64; ++k) {
    float4 xv = *(const float4*)&sXt[k * 68 + r4 * 4];
    float4 wv = *(const float4*)&sW[k * 64 + c4 * 4];
    const float* xf = &xv.x;
    const float* wf = &wv.x;
    #pragma unroll
    for (int i = 0; i < 4; ++i)
      #pragma unroll
      for (int j = 0; j < 4; ++j) acc[i][j] += xf[i] * wf[j];
  }

  float attv[4];
  #pragma unroll
  for (int j = 0; j < 4; ++j) attv[j] = sAtt[c4 * 4 + j];
  int h = c4 >> 2;
  #pragma unroll
  for (int i = 0; i < 4; ++i) {
    int row = r0 + r4 * 4 + i;
    bool ok = row < Ns;
    if (ok) *(float4*)(hs + (size_t)row * 64 + c4 * 4) =
        make_float4(acc[i][0], acc[i][1], acc[i][2], acc[i][3]);
    float p = acc[i][0] * attv[0] + acc[i][1] * attv[1] +
              acc[i][2] * attv[2] + acc[i][3] * attv[3];
    p += __shfl_xor(p, 1, 64);
    p += __shfl_xor(p, 2, 64);
    if ((c4 & 3) == 0 && ok) a_s[(size_t)row * 4 + h] = p;
  }
}

// a_d = x_d @ vd (64x4 GEMV); vd folded from Wd,att per block.
__global__ __launch_bounds__(256) void k_ad(const float* __restrict__ x,
    const float* __restrict__ Wd, const float* __restrict__ att,
    float* __restrict__ a_d, int Nd)
{
  __shared__ float sV[256];
  int tid = threadIdx.x;
  {
    int k = tid >> 2, h = tid & 3;
    float s = 0.f;
    #pragma unroll
    for (int c = 0; c < 16; ++c) s += Wd[k * 64 + h * 16 + c] * att[h * 16 + c];
    sV[k * 4 + h] = s;
  }
  __syncthreads();
  int n = blockIdx.x * 256 + tid;
  if (n >= Nd) return;
  const float4* x4 = (const float4*)(x + (size_t)n * 64);
  float a0 = 0.f, a1 = 0.f, a2 = 0.f, a3 = 0.f;
  #pragma unroll
  for (int k4 = 0; k4 < 16; ++k4) {
    float4 xv = x4[k4];
    const float* f = &xv.x;
    #pragma unroll
    for (int j = 0; j < 4; ++j) {
      int k = k4 * 4 + j;
      float xk = f[j];
      a0 += xk * sV[k * 4 + 0];
      a1 += xk * sV[k * 4 + 1];
      a2 += xk * sV[k * 4 + 2];
      a3 += xk * sV[k * 4 + 3];
    }
  }
  *(float4*)(a_d + (size_t)n * 4) = make_float4(a0, a1, a2, a3);
}

// ---------------- CSR build: two-level LDS multisplit ----------------

// A1: per-chunk coarse histogram (bins of 1<<shift dst), LDS atomics only.
__global__ __launch_bounds__(256) void k_bhist(const int* __restrict__ col, int E,
    int nblk, int nbin, int shift, int* __restrict__ bh)
{
  __shared__ int h[1024];
  int tid = threadIdx.x;
  for (int j = tid; j < nbin; j += 256) h[j] = 0;
  __syncthreads();
  int b = blockIdx.x;
  int lo = b * CHUNK, hi = min(E, lo + CHUNK);
  for (int i = lo + tid; i < hi; i += 256) atomicAdd(&h[col[i] >> shift], 1);
  __syncthreads();
  for (int j = tid; j < nbin; j += 256) bh[j * nblk + b] = h[j];   // bin-major
}

// A2: parallel flat exclusive scan of bh[0 .. nbin*nblk) in 3 coalesced passes.
__global__ __launch_bounds__(256) void k_s1(const int* __restrict__ a,
    int* __restrict__ bsum, int n)
{
  __shared__ int tmp[256];
  int t = threadIdx.x;
  int base = blockIdx.x * 4096 + t * 16;
  int s = 0;
  #pragma unroll
  for (int i = 0; i < 16; ++i) { int idx = base + i; if (idx < n) s += a[idx]; }
  tmp[t] = s;
  __syncthreads();
  for (int off = 128; off > 0; off >>= 1) {
    if (t < off) tmp[t] += tmp[t + off];
    __syncthreads();
  }
  if (t == 0) bsum[blockIdx.x] = tmp[0];
}

__global__ __launch_bounds__(1024) void k_s2(int* __restrict__ bsum, int nb) {
  __shared__ int tmp[1024];
  int t = threadIdx.x;
  int v = (t < nb) ? bsum[t] : 0;
  tmp[t] = v;
  __syncthreads();
  for (int off = 1; off < 1024; off <<= 1) {
    int u = (t >= off) ? tmp[t - off] : 0;
    __syncthreads();
    tmp[t] += u;
    __syncthreads();
  }
  if (t < nb) bsum[t] = tmp[t] - v;   // exclusive
}

__global__ __launch_bounds__(256) void k_s3(int* __restrict__ a,
    const int* __restrict__ bsum, int n)
{
  __shared__ int tw[256];
  int t = threadIdx.x;
  int base = blockIdx.x * 4096 + t * 16;
  int v[16];
  int s = 0;
  #pragma unroll
  for (int i = 0; i < 16; ++i) { int idx = base + i; v[i] = (idx < n) ? a[idx] : 0; s += v[i]; }
  tw[t] = s;
  __syncthreads();
  for (int off = 1; off < 256; off <<= 1) {
    int u = (t >= off) ? tw[t - off] : 0;
    __syncthreads();
    tw[t] += u;
    __syncthreads();
  }
  int excl = bsum[blockIdx.x] + tw[t] - s;
  #pragma unroll
  for (int i = 0; i < 16; ++i) {
    int idx = base + i;
    if (idx < n) { a[idx] = excl; excl += v[i]; }
  }
}

// binbase[j] = global start of coarse bin j (= bh[j*nblk] after scan); [nbin]=E.
__global__ void k_binbase(const int* __restrict__ bh, int nblk, int nbin, int E,
                          int* __restrict__ binbase)
{
  int j = blockIdx.x * 256 + threadIdx.x;
  if (j < nbin) binbase[j] = bh[(size_t)j * nblk];
  if (j == nbin) binbase[nbin] = E;
}

// A3: scatter into coarse buckets; cursors = scanned bh (disjoint ranges/block).
__global__ __launch_bounds__(256) void k_bscat(const int* __restrict__ row,
    const int* __restrict__ col, int E, int nblk, int nbin, int shift,
    const int* __restrict__ bh,
    int* __restrict__ trow, int* __restrict__ tcol)
{
  __shared__ int cur[1024];
  int tid = threadIdx.x;
  int b = blockIdx.x;
  for (int j = tid; j < nbin; j += 256) cur[j] = bh[j * nblk + b];
  __syncthreads();
  int lo = b * CHUNK, hi = min(E, lo + CHUNK);
  for (int i = lo + tid; i < hi; i += 256) {
    int c = col[i];
    int p = atomicAdd(&cur[c >> shift], 1);
    trow[p] = row[i];
    if (tcol) tcol[p] = c;
  }
}

// B: one block per coarse bin: fine hist (256 dst) + LDS scan -> rowptr + rows.
__global__ __launch_bounds__(256) void k_fine(const int* __restrict__ trow,
    const int* __restrict__ tcol, const int* __restrict__ binbase,
    int* __restrict__ rowptr, int* __restrict__ rows, int Nd, int nbin)
{
  __shared__ int h[256], sc[256], cur[256];
  int tid = threadIdx.x;
  int bin = blockIdx.x;
  int s = binbase[bin], e = binbase[bin + 1];
  h[tid] = 0;
  __syncthreads();
  for (int k = s + tid; k < e; k += 256) atomicAdd(&h[tcol[k] & 255], 1);
  __syncthreads();
  int own = h[tid];
  sc[tid] = own;
  __syncthreads();
  for (int off = 1; off < 256; off <<= 1) {
    int t = (tid >= off) ? sc[tid - off] : 0;
    __syncthreads();
    sc[tid] += t;
    __syncthreads();
  }
  int excl = sc[tid] - own;
  int dst = bin * 256 + tid;
  if (dst < Nd) rowptr[dst] = s + excl;
  cur[tid] = s + excl;
  if (bin == 0 && tid == 0) rowptr[Nd] = binbase[nbin];
  __syncthreads();
  for (int k = s + tid; k < e; k += 256) {
    int p = atomicAdd(&cur[tcol[k] & 255], 1);
    rows[p] = trow[k];
  }
}

// small-Nd path: rowptr is just binbase (bins of 1).
__global__ void k_rp(const int* __restrict__ binbase, int* __restrict__ rowptr, int Nd) {
  int i = blockIdx.x * 256 + threadIdx.x;
  if (i <= Nd) rowptr[i] = binbase[i];
}

// ---------------- gather (online softmax) ----------------

__global__ __launch_bounds__(256) void k_gather16(const int* __restrict__ rowptr,
    const int* __restrict__ rows, const float* __restrict__ a_s,
    const float* __restrict__ a_d, const float* __restrict__ hs,
    float* __restrict__ out, int Nd)
{
  int tid = threadIdx.x;
  int g = tid >> 4, lane = tid & 15, h = lane >> 2;
  int n = blockIdx.x * 16 + g;
  if (n >= Nd) return;
  float adh = a_d[(size_t)n * 4 + h];
  int start = rowptr[n], end = rowptr[n + 1];
  float m = -INFINITY, den = 0.f;
  float ax = 0.f, ay = 0.f, az = 0.f, aw = 0.f;
  for (int k = start; k < end; ++k) {
    int row = rows[k];
    float v = a_s[(size_t)row * 4 + h] + adh;
    v = v >= 0.f ? v : 0.2f * v;
    float mn = fmaxf(m, v);
    float c = __expf(m - mn);
    float p = __expf(v - mn);
    float4 hv = *(const float4*)(hs + (size_t)row * 64 + lane * 4);
    den = den * c + p;
    ax = ax * c + p * hv.x;
    ay = ay * c + p * hv.y;
    az = az * c + p * hv.z;
    aw = aw * c + p * hv.w;
    m = mn;
  }
  float inv = 1.f / (den + 1e-16f);
  float4* op = (float4*)(out + (size_t)n * 64) + lane;
  float4 prev = *op;
  prev.x += ax * inv; prev.y += ay * inv; prev.z += az * inv; prev.w += aw * inv;
  *op = prev;
}

__global__ __launch_bounds__(256) void k_gatherB(const int* __restrict__ rowptr,
    const int* __restrict__ rows, const float* __restrict__ a_s,
    const float* __restrict__ a_d, const float* __restrict__ hs,
    float* __restrict__ out)
{
  __shared__ float sm[64], sden[64], sacc[1024];
  int n = blockIdx.x;
  int tid = threadIdx.x;
  int sg = tid >> 4, lane = tid & 15, h = lane >> 2;
  float adh = a_d[(size_t)n * 4 + h];
  int start = rowptr[n], end = rowptr[n + 1];
  float m = -INFINITY, den = 0.f;
  float ax = 0.f, ay = 0.f, az = 0.f, aw = 0.f;
  for (int k = start + sg; k < end; k += 16) {
    int row = rows[k];
    float v = a_s[(size_t)row * 4 + h] + adh;
    v = v >= 0.f ? v : 0.2f * v;
    float mn = fmaxf(m, v);
    float c = __expf(m - mn);
    float p = __expf(v - mn);
    float4 hv = *(const float4*)(hs + (size_t)row * 64 + lane * 4);
    den = den * c + p;
    ax = ax * c + p * hv.x;
    ay = ay * c + p * hv.y;
    az = az * c + p * hv.z;
    aw = aw * c + p * hv.w;
    m = mn;
  }
  sacc[sg * 64 + lane * 4 + 0] = ax;
  sacc[sg * 64 + lane * 4 + 1] = ay;
  sacc[sg * 64 + lane * 4 + 2] = az;
  sacc[sg * 64 + lane * 4 + 3] = aw;
  if ((lane & 3) == 0) { sm[sg * 4 + h] = m; sden[sg * 4 + h] = den; }
  __syncthreads();
  if (tid < 64) {
    int hh = tid >> 4;
    float M = -INFINITY;
    #pragma unroll
    for (int g2 = 0; g2 < 16; ++g2) M = fmaxf(M, sm[g2 * 4 + hh]);
    if (M == -INFINITY) M = 0.f;
    float D = 0.f, A = 0.f;
    #pragma unroll
    for (int g2 = 0; g2 < 16; ++g2) {
      float mv = sm[g2 * 4 + hh];
      float c = (mv == -INFINITY) ? 0.f : __expf(mv - M);
      D += sden[g2 * 4 + hh] * c;
      A += sacc[g2 * 64 + tid] * c;
    }
    out[(size_t)n * 64 + tid] += A / (D + 1e-16f);
  }
}

// ---------------- epilogue ----------------

__global__ void k_act(float* __restrict__ x, const float* __restrict__ b0,
                      const float* __restrict__ b1, const float* __restrict__ b2,
                      const float* __restrict__ b3, int nb, int n)
{
  int i = blockIdx.x * blockDim.x + threadIdx.x;
  if (i >= n) return;
  int d = i & 63;
  float bs = b0[d] + b1[d];
  if (nb == 4) bs += b2[d] + b3[d];
  float v = x[i] + bs;
  x[i] = v >= 0.f ? v : 0.01f * v;
}

__global__ void k_final(const float* __restrict__ x0, const float* __restrict__ x1,
                        const float* __restrict__ x2, float* __restrict__ out, int n)
{
  int i = blockIdx.x * blockDim.x + threadIdx.x;
  if (i < n) out[i] = (x0[i] + x1[i] + x2[i]) * (1.f / 3.f);
}

// ---------------- launch ----------------

extern "C" void kernel_launch(void* const* d_in, const int* in_sizes, int n_in,
                              void* d_out, int out_size, void* d_ws, size_t ws_size,
                              hipStream_t stream)
{
  static const int ECNT[8] = {1000000, 1000000, 500000, 500000, 100000, 100000, 500000, 500000};
  static const int ESRC[8] = {0, 1, 0, 0, 1, 2, 0, 2};   // 0=user 1=article 2=category
  static const int EDST[8] = {1, 0, 0, 0, 2, 1, 2, 0};
  const int NSZ[3] = {kNUser, kNArt, kNCat};

  const float* x0[3] = {(const float*)d_in[0], (const float*)d_in[1], (const float*)d_in[2]};
  const float* Wsrc = (const float*)d_in[3];
  const float* Wdst = (const float*)d_in[4];
  const float* attS = (const float*)d_in[5];
  const float* attD = (const float*)d_in[6];
  const float* bias = (const float*)d_in[7];
  const int* ei[8];
  for (int t = 0; t < 8; ++t) ei[t] = (const int*)d_in[8 + t];

  float* ws = (float*)d_ws;
  size_t off = 0;
  auto alloc = [&](size_t nelem) { float* p = ws + off; off += nelem; return p; };
  float* xb0 = alloc(SZ_X);
  float* xb1 = alloc(SZ_X);
  float* hs  = alloc((size_t)kNUser * 64);
  float* a_s = alloc((size_t)kNUser * 4);
  float* a_d = alloc((size_t)kNUser * 4);
  int* rowptrA = (int*)alloc(1001008);
  int* rowsA   = (int*)alloc(4200000);
  int* tmp_row = (int*)alloc(1000000);
  int* tmp_col = (int*)alloc(1000000);
  int* blockhist = (int*)alloc(200704);      // max nbin(782) * nblk(245)
  int* binbase   = (int*)alloc(1032);
  int* bsum      = (int*)alloc(1024);

  int* rowptr_t[8]; int* rows_t[8];
  {
    size_t ro = 0, eo = 0;
    for (int t = 0; t < 8; ++t) {
      int Nd = NSZ[EDST[t]];
      rowptr_t[t] = rowptrA + ro; ro += (size_t)Nd + 1;
      rows_t[t]   = rowsA + eo;   eo += (size_t)ECNT[t];
    }
  }

  // ---- CSR build: two-level LDS multisplit (no global atomics) ----
  for (int t = 0; t < 8; ++t) {
    int Nd = NSZ[EDST[t]], E = ECNT[t];
    const int* row = ei[t];
    const int* col = ei[t] + E;
    int shift = (Nd <= 1024) ? 0 : 8;
    int nbin = ((Nd - 1) >> shift) + 1;
    int nblk = (E + CHUNK - 1) / CHUNK;
    int n = nbin * nblk;
    int nb2 = (n + 4095) / 4096;
    k_bhist<<<nblk, 256, 0, stream>>>(col, E, nblk, nbin, shift, blockhist);
    k_s1<<<nb2, 256, 0, stream>>>(blockhist, bsum, n);
    k_s2<<<1, 1024, 0, stream>>>(bsum, nb2);
    k_s3<<<nb2, 256, 0, stream>>>(blockhist, bsum, n);
    k_binbase<<<(nbin + 256) / 256, 256, 0, stream>>>(blockhist, nblk, nbin, E, binbase);
    if (shift == 0) {
      // bins of 1 dst: coarse scatter is the final sort
      k_bscat<<<nblk, 256, 0, stream>>>(row, col, E, nblk, nbin, 0,
                                        blockhist, rows_t[t], nullptr);
      k_rp<<<(Nd + 256) / 256, 256, 0, stream>>>(binbase, rowptr_t[t], Nd);
    } else {
      k_bscat<<<nblk, 256, 0, stream>>>(row, col, E, nblk, nbin, 8,
                                        blockhist, tmp_row, tmp_col);
      k_fine<<<nbin, 256, 0, stream>>>(tmp_row, tmp_col, binbase,
                                       rowptr_t[t], rows_t[t], Nd, nbin);
    }
  }

  float* xb[2][3] = {{xb0, xb0 + SZ_U, xb0 + SZ_U + SZ_A},
                     {xb1, xb1 + SZ_U, xb1 + SZ_U + SZ_A}};
  const float* xcur[3] = {x0[0], x0[1], x0[2]};
  for (int l = 0; l < 2; ++l) {
    hipMemsetAsync(xb[l][0], 0, SZ_X * sizeof(float), stream);
    for (int t = 0; t < 8; ++t) {
      int s = ESRC[t], d = EDST[t];
      int Ns = NSZ[s], Nd = NSZ[d];
      const float* Ws = Wsrc + (size_t)(l * 8 + t) * 4096;
      const float* Wd = Wdst + (size_t)(l * 8 + t) * 4096;
      const float* aS = attS + (size_t)(l * 8 + t) * 64;
      const float* aD = attD + (size_t)(l * 8 + t) * 64;
      k_transform<<<(Ns + 63) / 64, 256, 0, stream>>>(xcur[s], Ws, aS, hs, a_s, Ns);
      k_ad<<<(Nd + 255) / 256, 256, 0, stream>>>(xcur[d], Wd, aD, a_d, Nd);
      if (Nd <= 512)
        k_gatherB<<<Nd, 256, 0, stream>>>(rowptr_t[t], rows_t[t], a_s, a_d, hs, xb[l][d]);
      else
        k_gather16<<<(Nd + 15) / 16, 256, 0, stream>>>(rowptr_t[t], rows_t[t], a_s, a_d, hs, xb[l][d], Nd);
    }
    const float* bl = bias + (size_t)l * 8 * 64;
    // dst lists: user {1,2,3,7}, article {0,5}, category {4,6}
    k_act<<<((int)SZ_U + 255) / 256, 256, 0, stream>>>(xb[l][0], bl + 64, bl + 128, bl + 192, bl + 448, 4, (int)SZ_U);
    k_act<<<((int)SZ_A + 255) / 256, 256, 0, stream>>>(xb[l][1], bl + 0,  bl + 320, bl, bl, 2, (int)SZ_A);
    k_act<<<((int)SZ_C + 255) / 256, 256, 0, stream>>>(xb[l][2], bl + 256, bl + 384, bl, bl, 2, (int)SZ_C);
    xcur[0] = xb[l][0]; xcur[1] = xb[l][1]; xcur[2] = xb[l][2];
  }
  k_final<<<((int)SZ_U + 255) / 256, 256, 0, stream>>>(x0[0], xb[0][0], xb[1][0], (float*)d_out, (int)SZ_U);
  k_final<<<((int)SZ_A + 255) / 256, 256, 0, stream>>>(x0[1], xb[0][1], xb[1][1], (float*)d_out + SZ_U, (int)SZ_A);
}